// Round 6
// baseline (154.365 us; speedup 1.0000x reference)
//
#include <hip/hip_runtime.h>
#include <math.h>

#define T_STEPS 3
#define N_NODES 100000
#define N_EDGES 1600000
#define N_E4    (N_EDGES / 4)
#define D 64

#define CS_BLOCKS 782       // ceil(100000/128) colsum blocks per t
#define HP_BLOCKS 98        // hist-partial blocks per t

// Bucketed-scatter parameters
#define BKT_BITS 9
#define BKT_SIZE 512
#define NBKT 196            // ceil(100000/512)
#define QSCALE 65536.0f     // 2^16
#define QINV   (1.0f / 65536.0f)

// Sorting-scatter parameters (512-thread blocks)
#define SC_EPB 4096         // edges per scatter block
#define SC_I4  1024         // int4 per scatter block
#define SC_BLOCKS 391       // ceil(400000 / 1024)

// Fallback (packed global atomic) parameters
#define PACK_SCALE 1048576.0f
#define PACK_INV   (1.0f / 1048576.0f)

// ---------------------------------------------------------------------------
// FAST ws layout (float offsets) — no memsets needed, all buffers are
// written before read every call:
//   [0,4800000)        recs[3][E] u32  ... ALSO (earlier in the pipeline):
//        [0,150144)        colsumP[3][782][64]   (K1 -> K3, dead before K5)
//        [150144,225408)   histP[3][98][256] u32 (K2 -> K3, dead before K5)
//   [4800000,4800768)  bucketStart[3][256] u32  (K3)
//   [4800768,4801536)  cursor[3][256] u32       (K3)
//   [4801536,4801728)  v[3][64]                 (K3)
//   [4801728,5101728)  s[3][N]                  (K4)
// ---------------------------------------------------------------------------

// K1: per-block column sums of x_t (no atomics).
__global__ __launch_bounds__(256) void colsum_part_kernel(const float* __restrict__ x,
                                                          float* __restrict__ colsumP) {
    const int t = blockIdx.y;
    const int tid = threadIdx.x;
    const int q = tid & 15;
    const int g = tid >> 4;
    const float4* xt = (const float4*)(x + (size_t)t * N_NODES * D);
    const int base = blockIdx.x * 128;
    float sx = 0.f, sy = 0.f, sz = 0.f, sw = 0.f;
#pragma unroll
    for (int it = 0; it < 8; ++it) {
        const int r = base + g + 16 * it;
        if (r < N_NODES) {
            const float4 vv = xt[(size_t)r * 16 + q];
            sx += vv.x; sy += vv.y; sz += vv.z; sw += vv.w;
        }
    }
    __shared__ float red[16][64];
    red[g][q * 4 + 0] = sx;
    red[g][q * 4 + 1] = sy;
    red[g][q * 4 + 2] = sz;
    red[g][q * 4 + 3] = sw;
    __syncthreads();
    if (tid < 64) {
        float s = 0.f;
#pragma unroll
        for (int gg = 0; gg < 16; ++gg) s += red[gg][tid];
        colsumP[((size_t)t * CS_BLOCKS + blockIdx.x) * 64 + tid] = s;
    }
}

// K2: per-block bucket histograms of dst (no global atomics).
__global__ __launch_bounds__(256) void hist_part_kernel(const int* __restrict__ dst,
                                                        unsigned* __restrict__ histP) {
    const int t = blockIdx.y;
    const int tid = threadIdx.x;
    __shared__ unsigned h[256];
    h[tid] = 0;
    __syncthreads();
    const int4* dp = (const int4*)(dst + (size_t)t * N_EDGES);
    const int base = blockIdx.x * 4096 + tid;
#pragma unroll
    for (int it = 0; it < 16; ++it) {
        const int i4 = base + it * 256;
        if (i4 < N_E4) {
            const int4 d = dp[i4];
            atomicAdd(&h[d.x >> BKT_BITS], 1u);
            atomicAdd(&h[d.y >> BKT_BITS], 1u);
            atomicAdd(&h[d.z >> BKT_BITS], 1u);
            atomicAdd(&h[d.w >> BKT_BITS], 1u);
        }
    }
    __syncthreads();
    histP[((size_t)t * HP_BLOCKS + blockIdx.x) * 256 + tid] = h[tid];
}

__device__ __forceinline__ float fast_sigmoid(float v) {
    return 1.f / (1.f + __expf(-v));
}
__device__ __forceinline__ float fast_tanh(float v) {
    return 1.f - 2.f / (__expf(2.f * v) + 1.f);
}

// K3 (2 blocks x 1024): block 0 = GRU chain (reduces colsumP itself),
// block 1 = histP reduction + exclusive scan -> bucketStart/cursor.
__global__ __launch_bounds__(1024) void gru_scan_kernel(
    const float* __restrict__ colsumP, const float* __restrict__ iw,
    const float* __restrict__ Wz, const float* __restrict__ bz,
    const float* __restrict__ Wr, const float* __restrict__ br,
    const float* __restrict__ Wh, const float* __restrict__ bh,
    const float* __restrict__ Wp, const float* __restrict__ bp,
    const float* __restrict__ Wo, const unsigned* __restrict__ histP,
    unsigned* __restrict__ bstart, unsigned* __restrict__ cursor,
    float* __restrict__ v_out, float* __restrict__ w_final) {
    const int tid = threadIdx.x;

    if (blockIdx.x == 1) {
        // ---- scan block ----
        __shared__ unsigned partU[1024];
        __shared__ unsigned scn[256];
        for (int t = 0; t < T_STEPS; ++t) {
            const int j = tid >> 8, b = tid & 255;
            unsigned p = 0;
            for (int k = j; k < HP_BLOCKS; k += 4)
                p += histP[((size_t)t * HP_BLOCKS + k) * 256 + b];
            partU[j * 256 + b] = p;
            __syncthreads();
            unsigned c = 0, v = 0;
            if (tid < 256) {
                c = partU[tid] + partU[256 + tid] + partU[512 + tid] + partU[768 + tid];
                v = c;
                scn[tid] = v;
            }
            __syncthreads();
            for (int off = 1; off < 256; off <<= 1) {
                unsigned add = 0;
                if (tid < 256 && tid >= off) add = scn[tid - off];
                __syncthreads();
                if (tid < 256) { v += add; scn[tid] = v; }
                __syncthreads();
            }
            if (tid < 256) {
                const unsigned st = (unsigned)(t * N_EDGES) + (v - c);
                bstart[t * 256 + tid] = st;
                cursor[t * 256 + tid] = st;
            }
            __syncthreads();
        }
        return;
    }

    // ---- GRU block ----
    __shared__ float wR[4096];    // w[i][k] row-major
    __shared__ float rwR[4096];   // (r*w)[i][k] row-major
    __shared__ float WzB[4096];   // Wz rows 64..127, [k][j]
    __shared__ float WrB[4096];
    __shared__ float WhB[4096];
    __shared__ float part[3072];
    __shared__ float sml[384];    // mean|ctx|czr[3][64]|wo
    float* mean_s = sml;
    float* ctx_s  = sml + 64;
    float* czr_s  = sml + 128;
    float* wo_s   = sml + 320;

    ((float4*)wR)[tid]  = ((const float4*)iw)[tid];
    ((float4*)WzB)[tid] = ((const float4*)(Wz + 4096))[tid];
    ((float4*)WrB)[tid] = ((const float4*)(Wr + 4096))[tid];
    ((float4*)WhB)[tid] = ((const float4*)(Wh + 4096))[tid];
    if (tid < 64) wo_s[tid] = Wo[tid];
    __syncthreads();

    const int j2 = (tid & 31) * 2;   // col pair
    const int i2 = (tid >> 5) * 2;   // row pair
    const int jm = tid & 63;         // matvec col
    const int g  = tid >> 6;         // matvec k-group

    float w00 = wR[i2 * 64 + j2],       w01 = wR[i2 * 64 + j2 + 1];
    float w10 = wR[(i2 + 1) * 64 + j2], w11 = wR[(i2 + 1) * 64 + j2 + 1];

    for (int t = 0; t < T_STEPS; ++t) {
        // reduce colsumP -> mean
        {
            float p = 0.f;
            for (int bx = g; bx < CS_BLOCKS; bx += 16)
                p += colsumP[((size_t)t * CS_BLOCKS + bx) * 64 + jm];
            part[g * 64 + jm] = p;
        }
        __syncthreads();
        if (tid < 64) {
            float s = 0.f;
#pragma unroll
            for (int gg = 0; gg < 16; ++gg) s += part[gg * 64 + tid];
            mean_s[tid] = s * (1.f / (float)N_NODES);
        }
        __syncthreads();
        // ctx = mean @ Wp + bp
        {
            float p = 0.f;
#pragma unroll
            for (int kk = 0; kk < 4; ++kk)
                p = fmaf(mean_s[4 * g + kk], Wp[(4 * g + kk) * 64 + jm], p);
            part[g * 64 + jm] = p;
        }
        __syncthreads();
        if (tid < 64) {
            float c = bp[tid];
#pragma unroll
            for (int gg = 0; gg < 16; ++gg) c += part[gg * 64 + tid];
            ctx_s[tid] = c;
        }
        __syncthreads();
        // cz/cr/ch = ctx @ {Wz,Wr,Wh}_top + biases
        {
            float p0 = 0.f, p1 = 0.f, p2 = 0.f;
#pragma unroll
            for (int kk = 0; kk < 4; ++kk) {
                const float c = ctx_s[4 * g + kk];
                const int o = (4 * g + kk) * 64 + jm;
                p0 = fmaf(c, Wz[o], p0);
                p1 = fmaf(c, Wr[o], p1);
                p2 = fmaf(c, Wh[o], p2);
            }
            part[g * 64 + jm] = p0;
            part[1024 + g * 64 + jm] = p1;
            part[2048 + g * 64 + jm] = p2;
        }
        __syncthreads();
        if (tid < 192) {
            const int m = tid >> 6, j = tid & 63;
            float c = (m == 0 ? bz[j] : (m == 1 ? br[j] : bh[j]));
#pragma unroll
            for (int gg = 0; gg < 16; ++gg) c += part[m * 1024 + gg * 64 + j];
            czr_s[m * 64 + j] = c;
        }
        __syncthreads();
        // z/r matmuls
        float z00 = 0, z01 = 0, z10 = 0, z11 = 0;
        float r00 = 0, r01 = 0, r10 = 0, r11 = 0;
        for (int k0 = 0; k0 < 64; k0 += 4) {
            const float4 a0 = *(const float4*)&wR[i2 * 64 + k0];
            const float4 a1 = *(const float4*)&wR[(i2 + 1) * 64 + k0];
            const float a0v[4] = {a0.x, a0.y, a0.z, a0.w};
            const float a1v[4] = {a1.x, a1.y, a1.z, a1.w};
#pragma unroll
            for (int kk = 0; kk < 4; ++kk) {
                const float2 bzv = *(const float2*)&WzB[(k0 + kk) * 64 + j2];
                const float2 brv = *(const float2*)&WrB[(k0 + kk) * 64 + j2];
                z00 = fmaf(a0v[kk], bzv.x, z00); z01 = fmaf(a0v[kk], bzv.y, z01);
                z10 = fmaf(a1v[kk], bzv.x, z10); z11 = fmaf(a1v[kk], bzv.y, z11);
                r00 = fmaf(a0v[kk], brv.x, r00); r01 = fmaf(a0v[kk], brv.y, r01);
                r10 = fmaf(a1v[kk], brv.x, r10); r11 = fmaf(a1v[kk], brv.y, r11);
            }
        }
        {
            const float cz0 = czr_s[j2], cz1 = czr_s[j2 + 1];
            const float cr0 = czr_s[64 + j2], cr1 = czr_s[64 + j2 + 1];
            z00 = fast_sigmoid(z00 + cz0); z01 = fast_sigmoid(z01 + cz1);
            z10 = fast_sigmoid(z10 + cz0); z11 = fast_sigmoid(z11 + cz1);
            r00 = fast_sigmoid(r00 + cr0); r01 = fast_sigmoid(r01 + cr1);
            r10 = fast_sigmoid(r10 + cr0); r11 = fast_sigmoid(r11 + cr1);
        }
        rwR[i2 * 64 + j2] = r00 * w00;       rwR[i2 * 64 + j2 + 1] = r01 * w01;
        rwR[(i2 + 1) * 64 + j2] = r10 * w10; rwR[(i2 + 1) * 64 + j2 + 1] = r11 * w11;
        __syncthreads();
        float h00 = 0, h01 = 0, h10 = 0, h11 = 0;
        for (int k0 = 0; k0 < 64; k0 += 4) {
            const float4 a0 = *(const float4*)&rwR[i2 * 64 + k0];
            const float4 a1 = *(const float4*)&rwR[(i2 + 1) * 64 + k0];
            const float a0v[4] = {a0.x, a0.y, a0.z, a0.w};
            const float a1v[4] = {a1.x, a1.y, a1.z, a1.w};
#pragma unroll
            for (int kk = 0; kk < 4; ++kk) {
                const float2 bhv = *(const float2*)&WhB[(k0 + kk) * 64 + j2];
                h00 = fmaf(a0v[kk], bhv.x, h00); h01 = fmaf(a0v[kk], bhv.y, h01);
                h10 = fmaf(a1v[kk], bhv.x, h10); h11 = fmaf(a1v[kk], bhv.y, h11);
            }
        }
        {
            const float ch0 = czr_s[128 + j2], ch1 = czr_s[128 + j2 + 1];
            h00 = fast_tanh(h00 + ch0); h01 = fast_tanh(h01 + ch1);
            h10 = fast_tanh(h10 + ch0); h11 = fast_tanh(h11 + ch1);
        }
        w00 = z00 * w00 + (1.f - z00) * h00;
        w01 = z01 * w01 + (1.f - z01) * h01;
        w10 = z10 * w10 + (1.f - z10) * h10;
        w11 = z11 * w11 + (1.f - z11) * h11;
        {
            const float wo0 = wo_s[j2], wo1 = wo_s[j2 + 1];
            float vp0 = w00 * wo0 + w01 * wo1;
            float vp1 = w10 * wo0 + w11 * wo1;
            vp0 += __shfl_xor(vp0, 1);  vp1 += __shfl_xor(vp1, 1);
            vp0 += __shfl_xor(vp0, 2);  vp1 += __shfl_xor(vp1, 2);
            vp0 += __shfl_xor(vp0, 4);  vp1 += __shfl_xor(vp1, 4);
            vp0 += __shfl_xor(vp0, 8);  vp1 += __shfl_xor(vp1, 8);
            vp0 += __shfl_xor(vp0, 16); vp1 += __shfl_xor(vp1, 16);
            if ((tid & 31) == 0) {
                v_out[t * 64 + i2]     = vp0;
                v_out[t * 64 + i2 + 1] = vp1;
            }
        }
        wR[i2 * 64 + j2] = w00;       wR[i2 * 64 + j2 + 1] = w01;
        wR[(i2 + 1) * 64 + j2] = w10; wR[(i2 + 1) * 64 + j2 + 1] = w11;
        __syncthreads();
    }
    w_final[i2 * 64 + j2] = w00;       w_final[i2 * 64 + j2 + 1] = w01;
    w_final[(i2 + 1) * 64 + j2] = w10; w_final[(i2 + 1) * 64 + j2 + 1] = w11;
}

// K4: s_t[n] = x_t[n] . v_t
__global__ __launch_bounds__(256) void smatvec_kernel(const float* __restrict__ x,
                                                      const float* __restrict__ v,
                                                      float* __restrict__ s) {
    const int t = blockIdx.y;
    const int tid = threadIdx.x;
    const int l4 = tid & 3;
    const int rloc = tid >> 2;
    __shared__ float vs[64];
    if (tid < 64) vs[tid] = v[t * 64 + tid];
    __syncthreads();
    const int row = blockIdx.x * 64 + rloc;
    if (row < N_NODES) {
        const float4* xr = (const float4*)(x + ((size_t)t * N_NODES + row) * D);
        float acc = 0.f;
#pragma unroll
        for (int i = 0; i < 4; ++i) {
            const int c = i * 4 + l4;
            const float4 xv = xr[c];
            acc += xv.x * vs[c * 4 + 0] + xv.y * vs[c * 4 + 1] +
                   xv.z * vs[c * 4 + 2] + xv.w * vs[c * 4 + 3];
        }
        acc += __shfl_xor(acc, 1);
        acc += __shfl_xor(acc, 2);
        if (l4 == 0) s[(size_t)t * N_NODES + row] = acc;
    }
}

// K5: block-sorted scatter, 512 threads / 28KB LDS -> 4 blocks/CU.
__global__ __launch_bounds__(512) void scatter_sort_kernel(
    const int* __restrict__ src, const int* __restrict__ dst,
    const float* __restrict__ s, unsigned* __restrict__ cursor,
    unsigned* __restrict__ recs) {
    const int t = blockIdx.y;
    const int tid = threadIdx.x;
    __shared__ unsigned recL[SC_EPB];
    __shared__ unsigned short bktL[SC_EPB];
    __shared__ unsigned bh[256];     // block histogram
    __shared__ unsigned sc[256];     // inclusive scan
    __shared__ unsigned lofs[256];   // running local offset
    __shared__ unsigned badj[256];   // global_base - local_base

    if (tid < 256) bh[tid] = 0;
    __syncthreads();

    const int4* sp = (const int4*)(src + (size_t)t * N_EDGES);
    const int4* dp = (const int4*)(dst + (size_t)t * N_EDGES);
    const float* st = s + (size_t)t * N_NODES;

    unsigned rec[8];
    int bkt[8];
#pragma unroll
    for (int k = 0; k < 8; ++k) bkt[k] = -1;

    const int i4base = blockIdx.x * SC_I4 + tid;
#pragma unroll
    for (int it = 0; it < 2; ++it) {
        const int i4 = i4base + it * 512;
        if (i4 < N_E4) {
            const int4 sv = sp[i4];
            const int4 dv = dp[i4];
            const int ss[4] = {sv.x, sv.y, sv.z, sv.w};
            const int dd[4] = {dv.x, dv.y, dv.z, dv.w};
#pragma unroll
            for (int j = 0; j < 4; ++j) {
                const int q = (int)llrintf(st[ss[j]] * QSCALE);
                const int b = dd[j] >> BKT_BITS;
                rec[it * 4 + j] = ((unsigned)(dd[j] & (BKT_SIZE - 1)) << 22) |
                                  ((unsigned)q & 0x3FFFFFu);
                bkt[it * 4 + j] = b;
                atomicAdd(&bh[b], 1u);
            }
        }
    }
    __syncthreads();
    // exclusive scan over 256 buckets
    if (tid < 256) sc[tid] = bh[tid];
    __syncthreads();
    for (int off = 1; off < 256; off <<= 1) {
        unsigned add = 0;
        if (tid < 256 && tid >= off) add = sc[tid - off];
        __syncthreads();
        if (tid < 256) sc[tid] += add;
        __syncthreads();
    }
    if (tid < 256) {
        const unsigned cnt = bh[tid];
        const unsigned ex = sc[tid] - cnt;
        lofs[tid] = ex;
        unsigned gb = 0;
        if (cnt) gb = atomicAdd(&cursor[t * 256 + tid], cnt);
        badj[tid] = gb - ex;   // mod 2^32 ok
    }
    __syncthreads();
    // reorder into LDS sorted by bucket
#pragma unroll
    for (int k = 0; k < 8; ++k) {
        if (bkt[k] >= 0) {
            const unsigned pos = atomicAdd(&lofs[bkt[k]], 1u);
            recL[pos] = rec[k];
            bktL[pos] = (unsigned short)bkt[k];
        }
    }
    __syncthreads();
    // writeout: consecutive i -> consecutive global within each bucket run
    const int nrec = min(SC_EPB, N_EDGES - blockIdx.x * SC_EPB);
    for (int i = tid; i < nrec; i += 512) {
        const unsigned b = bktL[i];
        recs[badj[b] + (unsigned)i] = recL[i];
    }
}

// K6: per-bucket LDS u64 accumulate + finalize output.
__global__ __launch_bounds__(256) void accum_kernel(const unsigned* __restrict__ recs,
                                                    const unsigned* __restrict__ start,
                                                    const float* __restrict__ bo,
                                                    float* __restrict__ out) {
    const int b = blockIdx.x;
    const int t = blockIdx.y;
    const int tid = threadIdx.x;
    __shared__ unsigned long long bins[BKT_SIZE];
    bins[tid] = 0ULL;
    bins[tid + 256] = 0ULL;
    __syncthreads();
    const unsigned s0 = start[t * 256 + b];
    const unsigned s1 = start[t * 256 + b + 1];
    for (unsigned i = s0 + tid; i < s1; i += 256) {
        const unsigned rec = recs[i];
        const unsigned dl = rec >> 22;
        const long long q = (long long)(((int)(rec << 10)) >> 10);
        atomicAdd(&bins[dl], (unsigned long long)((1ULL << 41) + (unsigned long long)q));
    }
    __syncthreads();
    const float bo0 = bo[0];
#pragma unroll
    for (int k = 0; k < 2; ++k) {
        const int i = tid + k * 256;
        const int node = b * BKT_SIZE + i;
        if (node < N_NODES) {
            const unsigned long long tot = bins[i];
            const unsigned long long deg = (tot + (1ULL << 40)) >> 41;
            const long long rem = (long long)(tot - (deg << 41));
            const float acc = (float)rem * QINV;
            out[(size_t)t * N_NODES + node] = bo0 + acc / fmaxf((float)deg, 1.f);
        }
    }
}

// ---------- fallback path: packed global atomics ----------

__global__ __launch_bounds__(256) void edge_kernel(const int* __restrict__ src,
                                                   const int* __restrict__ dst,
                                                   const float* __restrict__ s,
                                                   unsigned long long* __restrict__ packed) {
    const int t = blockIdx.y;
    const int e4 = blockIdx.x * 256 + threadIdx.x;
    if (e4 * 4 >= N_EDGES) return;
    const int4* sp = (const int4*)(src + (size_t)t * N_EDGES);
    const int4* dp = (const int4*)(dst + (size_t)t * N_EDGES);
    const float* st = s + (size_t)t * N_NODES;
    unsigned long long* pk = packed + (size_t)t * N_NODES;
    const int4 s4 = sp[e4];
    const int4 d4 = dp[e4];
    const float v0 = st[s4.x], v1 = st[s4.y], v2 = st[s4.z], v3 = st[s4.w];
    const unsigned long long base = 1ULL << 41;
    atomicAdd(&pk[d4.x], base + (unsigned long long)(long long)llrintf(v0 * PACK_SCALE));
    atomicAdd(&pk[d4.y], base + (unsigned long long)(long long)llrintf(v1 * PACK_SCALE));
    atomicAdd(&pk[d4.z], base + (unsigned long long)(long long)llrintf(v2 * PACK_SCALE));
    atomicAdd(&pk[d4.w], base + (unsigned long long)(long long)llrintf(v3 * PACK_SCALE));
}

__global__ __launch_bounds__(256) void out_kernel(const unsigned long long* __restrict__ packed,
                                                  const float* __restrict__ bo,
                                                  float* __restrict__ out) {
    const int i = blockIdx.x * 256 + threadIdx.x;
    if (i < T_STEPS * N_NODES) {
        const unsigned long long tot = packed[i];
        const unsigned long long deg = (tot + (1ULL << 40)) >> 41;
        const long long rem = (long long)(tot - (deg << 41));
        const float acc = (float)rem * PACK_INV;
        out[i] = bo[0] + acc / fmaxf((float)deg, 1.0f);
    }
}

extern "C" void kernel_launch(void* const* d_in, const int* in_sizes, int n_in,
                              void* d_out, int out_size, void* d_ws, size_t ws_size,
                              hipStream_t stream) {
    const float* x  = (const float*)d_in[0];
    const int* src  = (const int*)d_in[1];
    const int* dst  = (const int*)d_in[2];
    const float* iw = (const float*)d_in[3];
    const float* Wz = (const float*)d_in[4];
    const float* bz = (const float*)d_in[5];
    const float* Wr = (const float*)d_in[6];
    const float* br = (const float*)d_in[7];
    const float* Wh = (const float*)d_in[8];
    const float* bh = (const float*)d_in[9];
    const float* Wp = (const float*)d_in[10];
    const float* bp = (const float*)d_in[11];
    const float* Wo = (const float*)d_in[12];
    const float* bo = (const float*)d_in[13];
    float* out = (float*)d_out;   // [3*N outs][64*64 w_final]
    float* ws  = (float*)d_ws;

    const size_t FAST_NEED = (size_t)5101728 * sizeof(float);
    if (ws_size >= FAST_NEED) {
        unsigned* recs    = (unsigned*)ws;              // [0,4800000) u32
        float* colsumP    = ws;                         // [0,150144) dead before K5
        unsigned* histP   = (unsigned*)(ws + 150144);   // [150144,225408) dead before K5
        unsigned* bstart  = (unsigned*)(ws + 4800000);  // 768
        unsigned* cursor  = (unsigned*)(ws + 4800768);  // 768
        float* vbuf       = ws + 4801536;               // 192
        float* sbuf       = ws + 4801728;               // 300000

        colsum_part_kernel<<<dim3(CS_BLOCKS, 3), 256, 0, stream>>>(x, colsumP);
        hist_part_kernel<<<dim3(HP_BLOCKS, 3), 256, 0, stream>>>(dst, histP);
        gru_scan_kernel<<<2, 1024, 0, stream>>>(colsumP, iw, Wz, bz, Wr, br, Wh, bh,
                                                Wp, bp, Wo, histP, bstart, cursor,
                                                vbuf, out + (size_t)T_STEPS * N_NODES);
        smatvec_kernel<<<dim3(1563, 3), 256, 0, stream>>>(x, vbuf, sbuf);
        scatter_sort_kernel<<<dim3(SC_BLOCKS, 3), 512, 0, stream>>>(src, dst, sbuf,
                                                                    cursor, recs);
        accum_kernel<<<dim3(NBKT, 3), 256, 0, stream>>>(recs, bstart, bo, out);
    } else {
        float* colsumP = ws;                                        // 150144
        float* vbuf    = ws + 150144;                               // 192
        float* sbuf    = ws + 150336;                               // 300000
        unsigned long long* packed = (unsigned long long*)(ws + 450336); // 300000 u64

        hipMemsetAsync(packed, 0, (size_t)600000 * sizeof(float), stream);

        colsum_part_kernel<<<dim3(CS_BLOCKS, 3), 256, 0, stream>>>(x, colsumP);
        gru_scan_kernel<<<1, 1024, 0, stream>>>(colsumP, iw, Wz, bz, Wr, br, Wh, bh,
                                                Wp, bp, Wo, (unsigned*)nullptr,
                                                (unsigned*)nullptr, (unsigned*)nullptr,
                                                vbuf, out + (size_t)T_STEPS * N_NODES);
        smatvec_kernel<<<dim3(1563, 3), 256, 0, stream>>>(x, vbuf, sbuf);
        edge_kernel<<<dim3(1563, 3), 256, 0, stream>>>(src, dst, sbuf, packed);
        out_kernel<<<1172, 256, 0, stream>>>(packed, bo, out);
    }
}

// Round 7
// 114.008 us; speedup vs baseline: 1.3540x; 1.3540x over previous
//
#include <hip/hip_runtime.h>
#include <math.h>

#define T_STEPS 3
#define N_NODES 100000
#define N_EDGES 1600000
#define N_E4    (N_EDGES / 4)
#define D 64

#define CS_BLOCKS 782       // ceil(100000/128) colsum blocks per t
#define HP_BLOCKS 98        // hist-partial blocks per t

// Bucketed-scatter parameters
#define BKT_BITS 9
#define BKT_SIZE 512
#define NBKT 196            // ceil(100000/512)
#define QSCALE 65536.0f     // 2^16
#define QINV   (1.0f / 65536.0f)

// Sorting-scatter parameters (512-thread blocks)
#define SC_EPB 4096         // edges per scatter block
#define SC_I4  1024         // int4 per scatter block
#define SC_BLOCKS 391       // ceil(400000 / 1024)

// GRU-rows parameters
#define GR_PAD 68           // row pitch for transposed B tiles (16B-aligned, low conflict)

// Fallback (packed global atomic) parameters
#define PACK_SCALE 1048576.0f
#define PACK_INV   (1.0f / 1048576.0f)

// ---------------------------------------------------------------------------
// FAST ws layout (float offsets) — no memsets needed:
//   [0,4800000)        recs[3][E] u32  ... ALSO (earlier, dead before K5):
//        [0,150144)        colsumP[3][782][64]
//        [150144,225408)   histP[3][98][256] u32
//   [4800000,4800768)  bucketStart[3][256] u32
//   [4800768,4801536)  cursor[3][256] u32
//   [4801536,4801728)  v[3][64]
//   [4801728,5101728)  s[3][N]
// ---------------------------------------------------------------------------

// K1: per-block column sums of x_t (no atomics).
__global__ __launch_bounds__(256) void colsum_part_kernel(const float* __restrict__ x,
                                                          float* __restrict__ colsumP) {
    const int t = blockIdx.y;
    const int tid = threadIdx.x;
    const int q = tid & 15;
    const int g = tid >> 4;
    const float4* xt = (const float4*)(x + (size_t)t * N_NODES * D);
    const int base = blockIdx.x * 128;
    float sx = 0.f, sy = 0.f, sz = 0.f, sw = 0.f;
#pragma unroll
    for (int it = 0; it < 8; ++it) {
        const int r = base + g + 16 * it;
        if (r < N_NODES) {
            const float4 vv = xt[(size_t)r * 16 + q];
            sx += vv.x; sy += vv.y; sz += vv.z; sw += vv.w;
        }
    }
    __shared__ float red[16][64];
    red[g][q * 4 + 0] = sx;
    red[g][q * 4 + 1] = sy;
    red[g][q * 4 + 2] = sz;
    red[g][q * 4 + 3] = sw;
    __syncthreads();
    if (tid < 64) {
        float s = 0.f;
#pragma unroll
        for (int gg = 0; gg < 16; ++gg) s += red[gg][tid];
        colsumP[((size_t)t * CS_BLOCKS + blockIdx.x) * 64 + tid] = s;
    }
}

// K2: per-block bucket histograms of dst (no global atomics).
__global__ __launch_bounds__(256) void hist_part_kernel(const int* __restrict__ dst,
                                                        unsigned* __restrict__ histP) {
    const int t = blockIdx.y;
    const int tid = threadIdx.x;
    __shared__ unsigned h[256];
    h[tid] = 0;
    __syncthreads();
    const int4* dp = (const int4*)(dst + (size_t)t * N_EDGES);
    const int base = blockIdx.x * 4096 + tid;
#pragma unroll
    for (int it = 0; it < 16; ++it) {
        const int i4 = base + it * 256;
        if (i4 < N_E4) {
            const int4 d = dp[i4];
            atomicAdd(&h[d.x >> BKT_BITS], 1u);
            atomicAdd(&h[d.y >> BKT_BITS], 1u);
            atomicAdd(&h[d.z >> BKT_BITS], 1u);
            atomicAdd(&h[d.w >> BKT_BITS], 1u);
        }
    }
    __syncthreads();
    histP[((size_t)t * HP_BLOCKS + blockIdx.x) * 256 + tid] = h[tid];
}

__device__ __forceinline__ float fast_sigmoid(float v) {
    return 1.f / (1.f + __expf(-v));
}
__device__ __forceinline__ float fast_tanh(float v) {
    return 1.f - 2.f / (__expf(2.f * v) + 1.f);
}

// K3: row-parallel GRU. Blocks 0..15: 4 rows each (1 wave per row),
// all 3 time steps, no inter-block sync (weight evolution is row-local;
// ctx/czrh depend only on x means, precomputed redundantly per block).
// Block 16 (fast path only): histP reduction + exclusive scan.
__global__ __launch_bounds__(256) void gru_rows_kernel(
    const float* __restrict__ colsumP, const float* __restrict__ iw,
    const float* __restrict__ Wz, const float* __restrict__ bz,
    const float* __restrict__ Wr, const float* __restrict__ br,
    const float* __restrict__ Wh, const float* __restrict__ bh,
    const float* __restrict__ Wp, const float* __restrict__ bp,
    const float* __restrict__ Wo, const unsigned* __restrict__ histP,
    unsigned* __restrict__ bstart, unsigned* __restrict__ cursor,
    float* __restrict__ v_out, float* __restrict__ w_final) {
    const int tid = threadIdx.x;

    if (blockIdx.x == 16) {
        // ---- scan block ----
        __shared__ unsigned scn[256];
        for (int t = 0; t < T_STEPS; ++t) {
            unsigned c = 0;
            for (int k = 0; k < HP_BLOCKS; ++k)
                c += histP[((size_t)t * HP_BLOCKS + k) * 256 + tid];
            unsigned v = c;
            scn[tid] = v;
            __syncthreads();
            for (int off = 1; off < 256; off <<= 1) {
                const unsigned add = (tid >= off) ? scn[tid - off] : 0u;
                __syncthreads();
                v += add;
                scn[tid] = v;
                __syncthreads();
            }
            const unsigned st = (unsigned)(t * N_EDGES) + (v - c);
            bstart[t * 256 + tid] = st;
            cursor[t * 256 + tid] = st;
            __syncthreads();
        }
        return;
    }

    // ---- GRU rows block ----
    __shared__ float BzT[64 * GR_PAD];   // BzT[j][k] = Wz[64+k][j]
    __shared__ float BrT[64 * GR_PAD];
    __shared__ float BhT[64 * GR_PAD];
    __shared__ float w_lds[4 * 64];
    __shared__ float mean_s[192];        // [t][j]
    __shared__ float ctx_s[192];         // [t][j]
    __shared__ float czrh_s[576];        // [(t*3+m)][j], m=0:z 1:r 2:h

    // preload transposed bottom halves
#pragma unroll
    for (int it = 0; it < 16; ++it) {
        const int idx = it * 256 + tid;
        const int k = idx >> 6, j = idx & 63;
        BzT[j * GR_PAD + k] = Wz[(64 + k) * 64 + j];
        BrT[j * GR_PAD + k] = Wr[(64 + k) * 64 + j];
        BhT[j * GR_PAD + k] = Wh[(64 + k) * 64 + j];
    }
    // mean[t][j] = sum over colsumP partials / N
    if (tid < 192) {
        const int t = tid >> 6, j = tid & 63;
        float s = 0.f;
        for (int bx = 0; bx < CS_BLOCKS; ++bx)
            s += colsumP[((size_t)t * CS_BLOCKS + bx) * 64 + j];
        mean_s[tid] = s * (1.f / (float)N_NODES);
    }
    __syncthreads();
    // ctx[t] = mean[t] @ Wp + bp
    if (tid < 192) {
        const int t = tid >> 6, j = tid & 63;
        float c = bp[j];
        for (int k = 0; k < 64; ++k)
            c = fmaf(mean_s[t * 64 + k], Wp[k * 64 + j], c);
        ctx_s[tid] = c;
    }
    __syncthreads();
    // czrh[t][m] = ctx[t] @ {Wz,Wr,Wh}_top + {bz,br,bh}
    for (int co = (tid >> 6); co < 9; co += 4) {
        const int t = co / 3, m = co - 3 * t, j = tid & 63;
        const float* W = (m == 0) ? Wz : (m == 1) ? Wr : Wh;
        const float* bb = (m == 0) ? bz : (m == 1) ? br : bh;
        float c = bb[j];
        for (int k = 0; k < 64; ++k)
            c = fmaf(ctx_s[t * 64 + k], W[k * 64 + j], c);
        czrh_s[co * 64 + j] = c;
    }
    __syncthreads();

    const int wid = tid >> 6, lane = tid & 63;
    const int row = blockIdx.x * 4 + wid;     // 0..63
    float* wrow = &w_lds[wid * 64];
    float w = iw[row * 64 + lane];
    const float wo = Wo[lane];

    for (int t = 0; t < T_STEPS; ++t) {
        wrow[lane] = w;
        __syncthreads();
        float az = 0.f, ar = 0.f;
#pragma unroll
        for (int k0 = 0; k0 < 64; k0 += 4) {
            const float4 wv = *(const float4*)&wrow[k0];                 // broadcast
            const float4 z4 = *(const float4*)&BzT[lane * GR_PAD + k0];
            const float4 r4 = *(const float4*)&BrT[lane * GR_PAD + k0];
            az = fmaf(wv.x, z4.x, az); az = fmaf(wv.y, z4.y, az);
            az = fmaf(wv.z, z4.z, az); az = fmaf(wv.w, z4.w, az);
            ar = fmaf(wv.x, r4.x, ar); ar = fmaf(wv.y, r4.y, ar);
            ar = fmaf(wv.z, r4.z, ar); ar = fmaf(wv.w, r4.w, ar);
        }
        const float z = fast_sigmoid(az + czrh_s[(t * 3 + 0) * 64 + lane]);
        const float r = fast_sigmoid(ar + czrh_s[(t * 3 + 1) * 64 + lane]);
        const float rw = r * w;
        __syncthreads();
        wrow[lane] = rw;
        __syncthreads();
        float ah = 0.f;
#pragma unroll
        for (int k0 = 0; k0 < 64; k0 += 4) {
            const float4 wv = *(const float4*)&wrow[k0];                 // broadcast
            const float4 h4 = *(const float4*)&BhT[lane * GR_PAD + k0];
            ah = fmaf(wv.x, h4.x, ah); ah = fmaf(wv.y, h4.y, ah);
            ah = fmaf(wv.z, h4.z, ah); ah = fmaf(wv.w, h4.w, ah);
        }
        const float h = fast_tanh(ah + czrh_s[(t * 3 + 2) * 64 + lane]);
        w = z * w + (1.f - z) * h;
        // v_t[row] = sum_j w_new[row][j] * Wo[j]
        float vp = w * wo;
        vp += __shfl_xor(vp, 1);
        vp += __shfl_xor(vp, 2);
        vp += __shfl_xor(vp, 4);
        vp += __shfl_xor(vp, 8);
        vp += __shfl_xor(vp, 16);
        vp += __shfl_xor(vp, 32);
        if (lane == 0) v_out[t * 64 + row] = vp;
        __syncthreads();
    }
    w_final[row * 64 + lane] = w;
}

// K4: s_t[n] = x_t[n] . v_t
__global__ __launch_bounds__(256) void smatvec_kernel(const float* __restrict__ x,
                                                      const float* __restrict__ v,
                                                      float* __restrict__ s) {
    const int t = blockIdx.y;
    const int tid = threadIdx.x;
    const int l4 = tid & 3;
    const int rloc = tid >> 2;
    __shared__ float vs[64];
    if (tid < 64) vs[tid] = v[t * 64 + tid];
    __syncthreads();
    const int row = blockIdx.x * 64 + rloc;
    if (row < N_NODES) {
        const float4* xr = (const float4*)(x + ((size_t)t * N_NODES + row) * D);
        float acc = 0.f;
#pragma unroll
        for (int i = 0; i < 4; ++i) {
            const int c = i * 4 + l4;
            const float4 xv = xr[c];
            acc += xv.x * vs[c * 4 + 0] + xv.y * vs[c * 4 + 1] +
                   xv.z * vs[c * 4 + 2] + xv.w * vs[c * 4 + 3];
        }
        acc += __shfl_xor(acc, 1);
        acc += __shfl_xor(acc, 2);
        if (l4 == 0) s[(size_t)t * N_NODES + row] = acc;
    }
}

// K5: block-sorted scatter, 512 threads / 28KB LDS.
__global__ __launch_bounds__(512) void scatter_sort_kernel(
    const int* __restrict__ src, const int* __restrict__ dst,
    const float* __restrict__ s, unsigned* __restrict__ cursor,
    unsigned* __restrict__ recs) {
    const int t = blockIdx.y;
    const int tid = threadIdx.x;
    __shared__ unsigned recL[SC_EPB];
    __shared__ unsigned short bktL[SC_EPB];
    __shared__ unsigned bh[256];
    __shared__ unsigned sc[256];
    __shared__ unsigned lofs[256];
    __shared__ unsigned badj[256];

    if (tid < 256) bh[tid] = 0;
    __syncthreads();

    const int4* sp = (const int4*)(src + (size_t)t * N_EDGES);
    const int4* dp = (const int4*)(dst + (size_t)t * N_EDGES);
    const float* st = s + (size_t)t * N_NODES;

    unsigned rec[8];
    int bkt[8];
#pragma unroll
    for (int k = 0; k < 8; ++k) bkt[k] = -1;

    const int i4base = blockIdx.x * SC_I4 + tid;
#pragma unroll
    for (int it = 0; it < 2; ++it) {
        const int i4 = i4base + it * 512;
        if (i4 < N_E4) {
            const int4 sv = sp[i4];
            const int4 dv = dp[i4];
            const int ss[4] = {sv.x, sv.y, sv.z, sv.w};
            const int dd[4] = {dv.x, dv.y, dv.z, dv.w};
#pragma unroll
            for (int j = 0; j < 4; ++j) {
                const int q = (int)llrintf(st[ss[j]] * QSCALE);
                const int b = dd[j] >> BKT_BITS;
                rec[it * 4 + j] = ((unsigned)(dd[j] & (BKT_SIZE - 1)) << 22) |
                                  ((unsigned)q & 0x3FFFFFu);
                bkt[it * 4 + j] = b;
                atomicAdd(&bh[b], 1u);
            }
        }
    }
    __syncthreads();
    if (tid < 256) sc[tid] = bh[tid];
    __syncthreads();
    for (int off = 1; off < 256; off <<= 1) {
        unsigned add = 0;
        if (tid < 256 && tid >= off) add = sc[tid - off];
        __syncthreads();
        if (tid < 256) sc[tid] += add;
        __syncthreads();
    }
    if (tid < 256) {
        const unsigned cnt = bh[tid];
        const unsigned ex = sc[tid] - cnt;
        lofs[tid] = ex;
        unsigned gb = 0;
        if (cnt) gb = atomicAdd(&cursor[t * 256 + tid], cnt);
        badj[tid] = gb - ex;
    }
    __syncthreads();
#pragma unroll
    for (int k = 0; k < 8; ++k) {
        if (bkt[k] >= 0) {
            const unsigned pos = atomicAdd(&lofs[bkt[k]], 1u);
            recL[pos] = rec[k];
            bktL[pos] = (unsigned short)bkt[k];
        }
    }
    __syncthreads();
    const int nrec = min(SC_EPB, N_EDGES - blockIdx.x * SC_EPB);
    for (int i = tid; i < nrec; i += 512) {
        const unsigned b = bktL[i];
        recs[badj[b] + (unsigned)i] = recL[i];
    }
}

// K6: per-bucket LDS u64 accumulate + finalize output.
__global__ __launch_bounds__(256) void accum_kernel(const unsigned* __restrict__ recs,
                                                    const unsigned* __restrict__ start,
                                                    const float* __restrict__ bo,
                                                    float* __restrict__ out) {
    const int b = blockIdx.x;
    const int t = blockIdx.y;
    const int tid = threadIdx.x;
    __shared__ unsigned long long bins[BKT_SIZE];
    bins[tid] = 0ULL;
    bins[tid + 256] = 0ULL;
    __syncthreads();
    const unsigned s0 = start[t * 256 + b];
    const unsigned s1 = start[t * 256 + b + 1];
    for (unsigned i = s0 + tid; i < s1; i += 256) {
        const unsigned rec = recs[i];
        const unsigned dl = rec >> 22;
        const long long q = (long long)(((int)(rec << 10)) >> 10);
        atomicAdd(&bins[dl], (unsigned long long)((1ULL << 41) + (unsigned long long)q));
    }
    __syncthreads();
    const float bo0 = bo[0];
#pragma unroll
    for (int k = 0; k < 2; ++k) {
        const int i = tid + k * 256;
        const int node = b * BKT_SIZE + i;
        if (node < N_NODES) {
            const unsigned long long tot = bins[i];
            const unsigned long long deg = (tot + (1ULL << 40)) >> 41;
            const long long rem = (long long)(tot - (deg << 41));
            const float acc = (float)rem * QINV;
            out[(size_t)t * N_NODES + node] = bo0 + acc / fmaxf((float)deg, 1.f);
        }
    }
}

// ---------- fallback path: packed global atomics ----------

__global__ __launch_bounds__(256) void edge_kernel(const int* __restrict__ src,
                                                   const int* __restrict__ dst,
                                                   const float* __restrict__ s,
                                                   unsigned long long* __restrict__ packed) {
    const int t = blockIdx.y;
    const int e4 = blockIdx.x * 256 + threadIdx.x;
    if (e4 * 4 >= N_EDGES) return;
    const int4* sp = (const int4*)(src + (size_t)t * N_EDGES);
    const int4* dp = (const int4*)(dst + (size_t)t * N_EDGES);
    const float* st = s + (size_t)t * N_NODES;
    unsigned long long* pk = packed + (size_t)t * N_NODES;
    const int4 s4 = sp[e4];
    const int4 d4 = dp[e4];
    const float v0 = st[s4.x], v1 = st[s4.y], v2 = st[s4.z], v3 = st[s4.w];
    const unsigned long long base = 1ULL << 41;
    atomicAdd(&pk[d4.x], base + (unsigned long long)(long long)llrintf(v0 * PACK_SCALE));
    atomicAdd(&pk[d4.y], base + (unsigned long long)(long long)llrintf(v1 * PACK_SCALE));
    atomicAdd(&pk[d4.z], base + (unsigned long long)(long long)llrintf(v2 * PACK_SCALE));
    atomicAdd(&pk[d4.w], base + (unsigned long long)(long long)llrintf(v3 * PACK_SCALE));
}

__global__ __launch_bounds__(256) void out_kernel(const unsigned long long* __restrict__ packed,
                                                  const float* __restrict__ bo,
                                                  float* __restrict__ out) {
    const int i = blockIdx.x * 256 + threadIdx.x;
    if (i < T_STEPS * N_NODES) {
        const unsigned long long tot = packed[i];
        const unsigned long long deg = (tot + (1ULL << 40)) >> 41;
        const long long rem = (long long)(tot - (deg << 41));
        const float acc = (float)rem * PACK_INV;
        out[i] = bo[0] + acc / fmaxf((float)deg, 1.0f);
    }
}

extern "C" void kernel_launch(void* const* d_in, const int* in_sizes, int n_in,
                              void* d_out, int out_size, void* d_ws, size_t ws_size,
                              hipStream_t stream) {
    const float* x  = (const float*)d_in[0];
    const int* src  = (const int*)d_in[1];
    const int* dst  = (const int*)d_in[2];
    const float* iw = (const float*)d_in[3];
    const float* Wz = (const float*)d_in[4];
    const float* bz = (const float*)d_in[5];
    const float* Wr = (const float*)d_in[6];
    const float* br = (const float*)d_in[7];
    const float* Wh = (const float*)d_in[8];
    const float* bh = (const float*)d_in[9];
    const float* Wp = (const float*)d_in[10];
    const float* bp = (const float*)d_in[11];
    const float* Wo = (const float*)d_in[12];
    const float* bo = (const float*)d_in[13];
    float* out = (float*)d_out;   // [3*N outs][64*64 w_final]
    float* ws  = (float*)d_ws;

    const size_t FAST_NEED = (size_t)5101728 * sizeof(float);
    if (ws_size >= FAST_NEED) {
        unsigned* recs    = (unsigned*)ws;              // [0,4800000) u32
        float* colsumP    = ws;                         // [0,150144) dead before K5
        unsigned* histP   = (unsigned*)(ws + 150144);   // [150144,225408) dead before K5
        unsigned* bstart  = (unsigned*)(ws + 4800000);  // 768
        unsigned* cursor  = (unsigned*)(ws + 4800768);  // 768
        float* vbuf       = ws + 4801536;               // 192
        float* sbuf       = ws + 4801728;               // 300000

        colsum_part_kernel<<<dim3(CS_BLOCKS, 3), 256, 0, stream>>>(x, colsumP);
        hist_part_kernel<<<dim3(HP_BLOCKS, 3), 256, 0, stream>>>(dst, histP);
        gru_rows_kernel<<<17, 256, 0, stream>>>(colsumP, iw, Wz, bz, Wr, br, Wh, bh,
                                                Wp, bp, Wo, histP, bstart, cursor,
                                                vbuf, out + (size_t)T_STEPS * N_NODES);
        smatvec_kernel<<<dim3(1563, 3), 256, 0, stream>>>(x, vbuf, sbuf);
        scatter_sort_kernel<<<dim3(SC_BLOCKS, 3), 512, 0, stream>>>(src, dst, sbuf,
                                                                    cursor, recs);
        accum_kernel<<<dim3(NBKT, 3), 256, 0, stream>>>(recs, bstart, bo, out);
    } else {
        float* colsumP = ws;                                        // 150144
        float* vbuf    = ws + 150144;                               // 192
        float* sbuf    = ws + 150336;                               // 300000
        unsigned long long* packed = (unsigned long long*)(ws + 450336); // 300000 u64

        hipMemsetAsync(packed, 0, (size_t)600000 * sizeof(float), stream);

        colsum_part_kernel<<<dim3(CS_BLOCKS, 3), 256, 0, stream>>>(x, colsumP);
        gru_rows_kernel<<<16, 256, 0, stream>>>(colsumP, iw, Wz, bz, Wr, br, Wh, bh,
                                                Wp, bp, Wo, (unsigned*)nullptr,
                                                (unsigned*)nullptr, (unsigned*)nullptr,
                                                vbuf, out + (size_t)T_STEPS * N_NODES);
        smatvec_kernel<<<dim3(1563, 3), 256, 0, stream>>>(x, vbuf, sbuf);
        edge_kernel<<<dim3(1563, 3), 256, 0, stream>>>(src, dst, sbuf, packed);
        out_kernel<<<1172, 256, 0, stream>>>(packed, bo, out);
    }
}